// Round 1
// 9296.342 us; speedup vs baseline: 1.0451x; 1.0451x over previous
//
#include <hip/hip_runtime.h>

// HMM forward: alpha_t = (alpha_{t-1} @ A) * B[:, obs_t], out = sum(alpha_{T-1})
// S=2048, V=32768, T=4096. Persistent cooperative kernel.
//
// R5 = R4's comm skeleton (proven: 128 blocks x 512 threads, 4 poll
// entries/thread, TWO barriers, single-wave coalesced 128B publish, A in
// 128KB LDS, per-step A fragments pinned in regs before the poll) with the
// dot phase restructured to C=4 columns/thread:
//   - thread (rg=tid>>2, cq=tid&3) computes rows rg*16..+15 x cols 4cq..+3
//   - A fragment af[16] = 16 rows x 4 cols (same 64 VGPRs as R4)
//   - alpha read: 4 ds_read_b128/thread instead of 16 -> critical-path LDS
//     instrs per CU/step drop 128->32 (~640ns -> ~160ns)
// A LDS layout: float4 = 4 consecutive cols of one row, slot XOR-swizzled by
// (row>>4)&7 (else 16-row rg-stride is bank-degenerate). alpha pad p+(p>>2)
// (rg*5 stride covers all 8 bank-quads). Both verified at the b128 floor.
//
// Evidence trail:
//  - R1/R3: per-wave scattered publish => partial-line write-throughs
//    serializing the critical path. NEVER do that.
//  - R4: 9715us = 2.37us/step; VALUBusy 10.4%, HBM 1%. Latency-bound:
//    poll roundtrip ~1.0-1.3us + dot 0.64us (LDS-bound) + tail.

#define S 2048
#define V 32768
#define T 4096
#define G 128          // blocks, cooperative, 1 per CU (LDS-capped)
#define BT 512         // 8 waves
#define COLS 16        // columns of A per block
#define RING 16        // b-value ring slots
#define DIST 8         // b prefetch distance (steps)

// LDS floats: As 32768 | al4 2560 (pad p+(p>>2), max idx 638 f4) | bring 256
//             | wpart 128 | fpart 8
#define SM_AS    0
#define SM_AL    32768
#define SM_BR    (SM_AL + 2560)
#define SM_WP    (SM_BR + RING * COLS)
#define SM_FP    (SM_WP + 8 * COLS)
#define SMEM_FLOATS (SM_FP + 8)
#define SMEM_BYTES  (SMEM_FLOATS * 4)   // 142,880 B < 160 KiB

__global__ __launch_bounds__(BT, 1) void hmm_fwd(
    const int* __restrict__ obs,
    const float* __restrict__ A,
    const float* __restrict__ B,
    const float* __restrict__ pi,
    float* __restrict__ out,
    unsigned long long* __restrict__ buf)   // 2 * S pairs of {tag32, f32}
{
    extern __shared__ float smem[];
    float4* As4    = (float4*)(smem + SM_AS);  // slot(row,u) = (row*4+u)^((row>>4)&7)
    float4* al4    = (float4*)(smem + SM_AL);  // idx p -> p + (p>>2)
    float*  bring  = smem + SM_BR;
    float*  wpart  = smem + SM_WP;
    float*  fpart  = smem + SM_FP;

    const int g    = blockIdx.x;
    const int tid  = threadIdx.x;
    const int lane = tid & 63;
    const int wave = tid >> 6;
    const int cq   = tid & 3;             // column quad: cols 4cq..4cq+3
    const int rg   = tid >> 2;            // row group 0..127 (rows rg*16..+15)

    // ---- one-time: stage A slice into LDS.
    // Read: float4 across 4 consecutive columns of one row (coalesced).
    // Write: ONE b128 to the XOR-swizzled slot (no scalar scatter needed).
    {
        const int u  = tid & 3;           // cols 4u..4u+3
        const int r0 = tid >> 2;          // rows, 128 per sweep
        for (int it = 0; it < 16; ++it) {
            int r = r0 + 128 * it;
            float4 av = *(const float4*)(A + (size_t)r * S + g * COLS + 4 * u);
            As4[(r * 4 + u) ^ ((r >> 4) & 7)] = av;
        }
    }

    // ---- wave 1: init b-ring (t=1..DIST). wave 0: publish alpha_0 (tag 1).
    if (wave == 1 && lane < COLS) {
        int jj = g * COLS + lane;
        for (int u = 1; u <= DIST; ++u) {
            int o = obs[u];
            bring[(u & (RING - 1)) * COLS + lane] = B[(size_t)jj * V + o];
        }
    }
    if (wave == 0 && lane < COLS) {
        int jl = g * COLS + lane;
        int o0 = obs[0];
        float v = pi[jl] * B[(size_t)jl * V + o0];
        unsigned long long p = (1ull << 32) | (unsigned long long)__float_as_uint(v);
        __hip_atomic_store(&buf[jl], p, __ATOMIC_RELAXED, __HIP_MEMORY_SCOPE_AGENT);
    }

    __syncthreads();   // A staged (and ring init ordered) before first use

    for (int t = 1; t < T; ++t) {
        // ---- A-fragment prefetch: rows rg*16..+15, cols 4cq..4cq+3, from LDS,
        // issued BEFORE the poll so the poll wait absorbs the LDS latency.
        float4 af[16];
#pragma unroll
        for (int r = 0; r < 16; ++r)
            af[r] = As4[((rg * 16 + r) * 4 + cq) ^ (rg & 7)];
#pragma unroll
        for (int r = 0; r < 16; ++r)
            asm volatile("" : "+v"(af[r].x), "+v"(af[r].y),
                              "+v"(af[r].z), "+v"(af[r].w));

        // ---- poll alpha_{t-1} (tag == t); 4 entries per thread (32B)
        unsigned long long want = (unsigned long long)t;
        unsigned long long* src = buf + (((t - 1) & 1) * S) + 4 * tid;
        unsigned long long v0, v1, v2, v3;
        for (;;) {
            v0 = __hip_atomic_load(&src[0], __ATOMIC_RELAXED, __HIP_MEMORY_SCOPE_AGENT);
            v1 = __hip_atomic_load(&src[1], __ATOMIC_RELAXED, __HIP_MEMORY_SCOPE_AGENT);
            v2 = __hip_atomic_load(&src[2], __ATOMIC_RELAXED, __HIP_MEMORY_SCOPE_AGENT);
            v3 = __hip_atomic_load(&src[3], __ATOMIC_RELAXED, __HIP_MEMORY_SCOPE_AGENT);
            if ((v0 >> 32) == want && (v1 >> 32) == want &&
                (v2 >> 32) == want && (v3 >> 32) == want) break;
            __builtin_amdgcn_s_sleep(1);
        }
        float4 f;
        f.x = __uint_as_float((unsigned)v0);
        f.y = __uint_as_float((unsigned)v1);
        f.z = __uint_as_float((unsigned)v2);
        f.w = __uint_as_float((unsigned)v3);
        al4[tid + (tid >> 2)] = f;        // padded stage
        __syncthreads();   // B1: alpha staged

        // ---- b prefetch for t+DIST (wave 1, off critical path)
        if (wave == 1 && lane < COLS) {
            int tp = t + DIST;
            if (tp < T) {
                int o = obs[tp];
                bring[(tp & (RING - 1)) * COLS + lane] =
                    B[(size_t)(g * COLS + lane) * V + o];
            }
        }

        // ---- dot: 16 rows x 4 cols; A in regs, alpha 4x ds_read_b128
        float4 acc = {0.f, 0.f, 0.f, 0.f};
#pragma unroll
        for (int k = 0; k < 4; ++k) {
            int p = rg * 4 + k;
            float4 al = al4[p + (p >> 2)];
            float4 a0 = af[4 * k + 0];
            float4 a1 = af[4 * k + 1];
            float4 a2 = af[4 * k + 2];
            float4 a3 = af[4 * k + 3];
            acc.x = fmaf(al.x, a0.x, acc.x);
            acc.x = fmaf(al.y, a1.x, acc.x);
            acc.x = fmaf(al.z, a2.x, acc.x);
            acc.x = fmaf(al.w, a3.x, acc.x);
            acc.y = fmaf(al.x, a0.y, acc.y);
            acc.y = fmaf(al.y, a1.y, acc.y);
            acc.y = fmaf(al.z, a2.y, acc.y);
            acc.y = fmaf(al.w, a3.y, acc.y);
            acc.z = fmaf(al.x, a0.z, acc.z);
            acc.z = fmaf(al.y, a1.z, acc.z);
            acc.z = fmaf(al.z, a2.z, acc.z);
            acc.z = fmaf(al.w, a3.z, acc.z);
            acc.w = fmaf(al.x, a0.w, acc.w);
            acc.w = fmaf(al.y, a1.w, acc.w);
            acc.w = fmaf(al.z, a2.w, acc.w);
            acc.w = fmaf(al.w, a3.w, acc.w);
        }
        // lane = rg_local*4 + cq; reduce across 16 rg_locals within the wave
#pragma unroll
        for (int off = 32; off >= 4; off >>= 1) {
            acc.x += __shfl_down(acc.x, off, 64);
            acc.y += __shfl_down(acc.y, off, 64);
            acc.z += __shfl_down(acc.z, off, 64);
            acc.w += __shfl_down(acc.w, off, 64);
        }
        if (lane < 4)   // rg_local==0: holds cols lane*4..lane*4+3
            *(float4*)(wpart + wave * 16 + lane * 4) = acc;
        __syncthreads();   // B2: partials ready

        // ---- epilogue: wave 0 sums, applies b_t, ONE coalesced 128B publish
        if (wave == 0 && lane < 16) {
            float s = 0.f;
#pragma unroll
            for (int w = 0; w < 8; ++w) s += wpart[w * 16 + lane];
            float val = s * bring[(t & (RING - 1)) * COLS + lane];
            unsigned long long p = (((unsigned long long)(t + 1)) << 32) |
                                   (unsigned long long)__float_as_uint(val);
            __hip_atomic_store(&buf[(t & 1) * S + g * COLS + lane], p,
                               __ATOMIC_RELAXED, __HIP_MEMORY_SCOPE_AGENT);
        }
    }

    // ---- final: block 0 sums alpha_{T-1} (tag == T) into out[0]
    if (g == 0) {
        unsigned long long want = (unsigned long long)T;
        unsigned long long* src = buf + (((T - 1) & 1) * S) + 4 * tid;
        unsigned long long v0, v1, v2, v3;
        for (;;) {
            v0 = __hip_atomic_load(&src[0], __ATOMIC_RELAXED, __HIP_MEMORY_SCOPE_AGENT);
            v1 = __hip_atomic_load(&src[1], __ATOMIC_RELAXED, __HIP_MEMORY_SCOPE_AGENT);
            v2 = __hip_atomic_load(&src[2], __ATOMIC_RELAXED, __HIP_MEMORY_SCOPE_AGENT);
            v3 = __hip_atomic_load(&src[3], __ATOMIC_RELAXED, __HIP_MEMORY_SCOPE_AGENT);
            if ((v0 >> 32) == want && (v1 >> 32) == want &&
                (v2 >> 32) == want && (v3 >> 32) == want) break;
            __builtin_amdgcn_s_sleep(1);
        }
        float sm = __uint_as_float((unsigned)v0) + __uint_as_float((unsigned)v1) +
                   __uint_as_float((unsigned)v2) + __uint_as_float((unsigned)v3);
        sm += __shfl_down(sm, 32, 64);
        sm += __shfl_down(sm, 16, 64);
        sm += __shfl_down(sm, 8, 64);
        sm += __shfl_down(sm, 4, 64);
        sm += __shfl_down(sm, 2, 64);
        sm += __shfl_down(sm, 1, 64);
        if (lane == 0) fpart[wave] = sm;
        __syncthreads();
        if (tid == 0) {
            float tot = 0.f;
            for (int w = 0; w < 8; ++w) tot += fpart[w];
            out[0] = tot;
        }
    }
}

extern "C" void kernel_launch(void* const* d_in, const int* in_sizes, int n_in,
                              void* d_out, int out_size, void* d_ws, size_t ws_size,
                              hipStream_t stream) {
    const int*   obs = (const int*)d_in[0];
    const float* A   = (const float*)d_in[1];
    const float* B   = (const float*)d_in[2];
    const float* pi  = (const float*)d_in[3];
    float* out = (float*)d_out;
    unsigned long long* buf = (unsigned long long*)d_ws;  // 2*S*8 = 32 KB

    hipFuncSetAttribute((const void*)hmm_fwd,
                        hipFuncAttributeMaxDynamicSharedMemorySize, SMEM_BYTES);

    // No memset needed: 0xAA poison tag 0xAAAAAAAA never matches tags [1,4096].

    void* args[] = { (void*)&obs, (void*)&A, (void*)&B, (void*)&pi,
                     (void*)&out, (void*)&buf };
    hipLaunchCooperativeKernel((void*)hmm_fwd, dim3(G), dim3(BT), args,
                               SMEM_BYTES, stream);
}